// Round 1
// baseline (1461.809 us; speedup 1.0000x reference)
//
#include <hip/hip_runtime.h>
#include <hip/hip_bf16.h>

typedef unsigned short u16;
typedef unsigned int   u32;

// ---------- helpers ----------
__device__ __forceinline__ float bf2f(u16 u) {
  return __uint_as_float(((u32)u) << 16);
}
__device__ __forceinline__ u16 f2bf(float f) {  // RNE
  u32 u = __float_as_uint(f);
  u += 0x7fffu + ((u >> 16) & 1u);
  return (u16)(u >> 16);
}
__device__ __forceinline__ u32 pack2(float a, float b) {
  return (u32)f2bf(a) | ((u32)f2bf(b) << 16);
}

// Problem constants
#define TOK_M   78848   // B*N = 8*9856
#define DIM     256
#define NWIN    1024    // 8 * 8 * 16
#define WINL    77      // 7*11

// ---------- LayerNorm (+ optional window-partition permutation), fp32 in, bf16 out ----------
// one wave per token; lane holds 4 channels (64*4 = 256)
template<bool PERM>
__global__ __launch_bounds__(256)
void ln_k(const float* __restrict__ X, const float* __restrict__ g,
          const float* __restrict__ bta, u16* __restrict__ Y)
{
  const int tid  = threadIdx.x;
  const int tok  = blockIdx.x * 4 + (tid >> 6);
  const int lane = tid & 63;
  float4 v = *(const float4*)(X + (size_t)tok * DIM + lane * 4);
  float s = v.x + v.y + v.z + v.w;
#pragma unroll
  for (int off = 32; off; off >>= 1) s += __shfl_xor(s, off);
  const float mu = s * (1.f / 256.f);
  const float dx = v.x - mu, dy = v.y - mu, dz = v.z - mu, dw = v.w - mu;
  float q = dx * dx + dy * dy + dz * dz + dw * dw;
#pragma unroll
  for (int off = 32; off; off >>= 1) q += __shfl_xor(q, off);
  const float rstd = rsqrtf(q * (1.f / 256.f) + 1e-5f);
  float4 gg = *(const float4*)(g + lane * 4);
  float4 bb = *(const float4*)(bta + lane * 4);
  const float y0 = dx * rstd * gg.x + bb.x;
  const float y1 = dy * rstd * gg.y + bb.y;
  const float y2 = dz * rstd * gg.z + bb.z;
  const float y3 = dw * rstd * gg.w + bb.w;
  size_t dest = (size_t)tok;
  if (PERM) {
    // (b, y*176+xc) -> window row ((b*8+ih)*16+iw)*77 + r*11 + c
    const int b  = tok / 9856, n = tok - b * 9856;
    const int y  = n / 176,  xc = n - y * 176;
    const int ih = y / 7,    rr = y - ih * 7;
    const int iw = xc / 11,  cc = xc - iw * 11;
    dest = (size_t)(((b * 8 + ih) * 16 + iw)) * 77 + rr * 11 + cc;
  }
  uint2 o;
  o.x = pack2(y0, y1);
  o.y = pack2(y2, y3);
  *(uint2*)(Y + dest * DIM + lane * 4) = o;
}

// ---------- Generic NT GEMM: C[M,N] = A(bf16)[M,K] @ W(f32)[N,K]^T + bias (+epilogue) ----------
// 128x128 block tile, 256 threads, 8x8 micro-tile per thread, BK=32.
// EPI: 0 = none, 1 = +res (f32, row-aligned), 2 = exact GELU.  OBF: 1 = bf16 out, 0 = f32 out.
template<int EPI, int OBF>
__global__ __launch_bounds__(256, 2)
void gemm_nt(const u16* __restrict__ A, const float* __restrict__ W,
             const float* __restrict__ bias, const float* __restrict__ res,
             void* __restrict__ Cout, int N, int K)
{
  __shared__ float As[32][128];
  __shared__ float Bs[32][128];
  const int tid = threadIdx.x;
  const int m0 = blockIdx.x * 128;
  const int n0 = blockIdx.y * 128;
  const int w  = tid >> 6, lane = tid & 63;
  const int wy = w >> 1,  wx = w & 1;
  const int ly = lane >> 3, lx = lane & 7;
  const int ao = wy * 64 + ly * 8;   // row offset of micro-tile in block
  const int bo = wx * 64 + lx * 8;   // col offset
  const int sm = tid & 127;          // staging row
  const int sk = (tid >> 7) << 4;    // staging k offset (0 or 16)

  const u16*   Ab = A + (size_t)(m0 + sm) * K + sk;
  const float* Wb = W + (size_t)(n0 + sm) * K + sk;

  float acc[8][8];
#pragma unroll
  for (int r = 0; r < 8; ++r)
#pragma unroll
    for (int c = 0; c < 8; ++c) acc[r][c] = 0.f;

  for (int kt = 0; kt < K; kt += 32) {
    uint4  a0 = *(const uint4*)(Ab + kt);          // 8 bf16
    uint4  a1 = *(const uint4*)(Ab + kt + 8);      // 8 bf16
    float4 w0 = *(const float4*)(Wb + kt);
    float4 w1 = *(const float4*)(Wb + kt + 4);
    float4 w2 = *(const float4*)(Wb + kt + 8);
    float4 w3 = *(const float4*)(Wb + kt + 12);
    __syncthreads();   // previous iter's LDS reads done
    {
      u32 au[8] = {a0.x, a0.y, a0.z, a0.w, a1.x, a1.y, a1.z, a1.w};
#pragma unroll
      for (int i = 0; i < 8; ++i) {
        As[sk + 2 * i    ][sm] = __uint_as_float((au[i] & 0xffffu) << 16);
        As[sk + 2 * i + 1][sm] = __uint_as_float(au[i] & 0xffff0000u);
      }
      float wv[16] = {w0.x, w0.y, w0.z, w0.w, w1.x, w1.y, w1.z, w1.w,
                      w2.x, w2.y, w2.z, w2.w, w3.x, w3.y, w3.z, w3.w};
#pragma unroll
      for (int i = 0; i < 16; ++i) Bs[sk + i][sm] = wv[i];
    }
    __syncthreads();
#pragma unroll 8
    for (int kk = 0; kk < 32; ++kk) {
      float4 A0 = *(const float4*)&As[kk][ao];
      float4 A1 = *(const float4*)&As[kk][ao + 4];
      float4 B0 = *(const float4*)&Bs[kk][bo];
      float4 B1 = *(const float4*)&Bs[kk][bo + 4];
      float av[8] = {A0.x, A0.y, A0.z, A0.w, A1.x, A1.y, A1.z, A1.w};
      float bv[8] = {B0.x, B0.y, B0.z, B0.w, B1.x, B1.y, B1.z, B1.w};
#pragma unroll
      for (int r = 0; r < 8; ++r)
#pragma unroll
        for (int c = 0; c < 8; ++c)
          acc[r][c] += av[r] * bv[c];
    }
  }

  const int gr = m0 + ao;
  const int gc = n0 + bo;
  float4 bb0 = *(const float4*)(bias + gc);
  float4 bb1 = *(const float4*)(bias + gc + 4);
  float bsv[8] = {bb0.x, bb0.y, bb0.z, bb0.w, bb1.x, bb1.y, bb1.z, bb1.w};
#pragma unroll
  for (int r = 0; r < 8; ++r) {
    const size_t row = (size_t)(gr + r);
    float v[8];
#pragma unroll
    for (int c = 0; c < 8; ++c) v[c] = acc[r][c] + bsv[c];
    if (EPI == 1) {
      float4 r0 = *(const float4*)(res + row * N + gc);
      float4 r1 = *(const float4*)(res + row * N + gc + 4);
      v[0] += r0.x; v[1] += r0.y; v[2] += r0.z; v[3] += r0.w;
      v[4] += r1.x; v[5] += r1.y; v[6] += r1.z; v[7] += r1.w;
    } else if (EPI == 2) {
#pragma unroll
      for (int c = 0; c < 8; ++c)
        v[c] = 0.5f * v[c] * (1.f + erff(v[c] * 0.70710678118654752f));
    }
    if (OBF) {
      u16* C = (u16*)Cout;
      uint4 o;
      o.x = pack2(v[0], v[1]); o.y = pack2(v[2], v[3]);
      o.z = pack2(v[4], v[5]); o.w = pack2(v[6], v[7]);
      *(uint4*)(C + row * N + gc) = o;
    } else {
      float* C = (float*)Cout;
      *(float4*)(C + row * N + gc)     = make_float4(v[0], v[1], v[2], v[3]);
      *(float4*)(C + row * N + gc + 4) = make_float4(v[4], v[5], v[6], v[7]);
    }
  }
}

// ---------- Windowed attention, one block per (window, head) ----------
// qkv: bf16 [NWIN*77, 768] (q|k|v concatenated). Writes o in NATURAL token order
// (window-reverse applied at store), bf16 [TOK_M, 256].
__global__ __launch_bounds__(256)
void attn_win(const u16* __restrict__ qkv, u16* __restrict__ onat)
{
  // region layout (62720 B total):
  //   vs[80][32] fp32 (v, row-major, zero-padded rows 77..79)
  //   ss[80][80] raw scores
  //   regC: phase1 = q^T[32][84] + k^T[32][84]; phase2 = p^T[80][84]
  __shared__ float vs[80][32];
  __shared__ float ss[80][80];
  __shared__ float regC[6720];

  const int tid  = threadIdx.x;
  const int nw   = blockIdx.x;
  const int head = blockIdx.y;
  const size_t base = (size_t)nw * 77 * 768;
  const int hoff = head * 32;

  float* qs = regC;              // qs[d*84 + l]
  float* ks = regC + 32 * 84;    // ks[d*84 + l]

  // ---- load q,k,v (bf16 -> f32), q/k transposed, zero-pad l = 77..79 ----
  for (int idx = tid; idx < 80 * 16; idx += 256) {
    const int l = idx >> 4;
    const int d = (idx & 15) << 1;
    float q0 = 0.f, q1 = 0.f, k0 = 0.f, k1 = 0.f, v0 = 0.f, v1 = 0.f;
    if (l < 77) {
      const u32* p = (const u32*)(qkv + base + (size_t)l * 768 + hoff + d);
      const u32 qu = p[0], ku = p[128], vu = p[256];
      q0 = __uint_as_float((qu & 0xffffu) << 16); q1 = __uint_as_float(qu & 0xffff0000u);
      k0 = __uint_as_float((ku & 0xffffu) << 16); k1 = __uint_as_float(ku & 0xffff0000u);
      v0 = __uint_as_float((vu & 0xffffu) << 16); v1 = __uint_as_float(vu & 0xffff0000u);
    }
    qs[(d    ) * 84 + l] = q0;
    qs[(d + 1) * 84 + l] = q1;
    ks[(d    ) * 84 + l] = k0;
    ks[(d + 1) * 84 + l] = k1;
    vs[l][d    ] = v0;
    vs[l][d + 1] = v1;
  }
  __syncthreads();

  // ---- scores: 4x4 tiles over 80x80, outer-product from transposed q/k ----
  const float scale = 0.17677669529663687f;  // 1/sqrt(32)
  for (int t = tid; t < 400; t += 256) {
    const int ti = t / 20, tj = t - ti * 20;
    const int i0 = ti * 4, j0 = tj * 4;
    float acc[4][4] = {{0.f}};
#pragma unroll
    for (int d = 0; d < 32; d += 4) {
#pragma unroll
      for (int dd = 0; dd < 4; ++dd) {
        float4 q4 = *(const float4*)&qs[(d + dd) * 84 + i0];
        float4 k4 = *(const float4*)&ks[(d + dd) * 84 + j0];
        const float qv[4] = {q4.x, q4.y, q4.z, q4.w};
        const float kv[4] = {k4.x, k4.y, k4.z, k4.w};
#pragma unroll
        for (int r = 0; r < 4; ++r)
#pragma unroll
          for (int c = 0; c < 4; ++c) acc[r][c] += qv[r] * kv[c];
      }
    }
#pragma unroll
    for (int r = 0; r < 4; ++r)
      *(float4*)&ss[i0 + r][j0] =
          make_float4(acc[r][0] * scale, acc[r][1] * scale,
                      acc[r][2] * scale, acc[r][3] * scale);
  }
  __syncthreads();

  // ---- softmax per row (wave-per-row), write transposed probs p^T into regC ----
  float* sst = regC;  // sst[j*84 + i]
  {
    const int wv = tid >> 6, lane = tid & 63;
    for (int i = wv; i < 77; i += 4) {
      const float v0 = ss[i][lane];
      const float v1 = (lane + 64 < 77) ? ss[i][lane + 64] : -1e30f;
      float mx = fmaxf(v0, v1);
#pragma unroll
      for (int off = 32; off; off >>= 1) mx = fmaxf(mx, __shfl_xor(mx, off));
      const float e0 = __expf(v0 - mx);
      const float e1 = __expf(v1 - mx);  // 0 for masked
      float s = e0 + e1;
#pragma unroll
      for (int off = 32; off; off >>= 1) s += __shfl_xor(s, off);
      const float inv = 1.f / s;
      sst[lane * 84 + i] = e0 * inv;
      if (lane + 64 < 80) sst[(lane + 64) * 84 + i] = e1 * inv;  // j=77..79 -> 0
    }
  }
  __syncthreads();

  // ---- O = P @ V : 4x4 tiles over 80 rows x 32 cols; write window-reversed ----
  const int b  = nw >> 7;
  const int ih = (nw >> 4) & 7;
  const int iw = nw & 15;
  for (int t = tid; t < 160; t += 256) {
    const int ti = t >> 3, tc = t & 7;
    const int i0 = ti * 4, d0 = tc * 4;
    float acc[4][4] = {{0.f}};
    for (int j = 0; j < 80; ++j) {
      float4 p4 = *(const float4*)&sst[j * 84 + i0];
      float4 v4 = *(const float4*)&vs[j][d0];
      const float pv[4] = {p4.x, p4.y, p4.z, p4.w};
      const float vv[4] = {v4.x, v4.y, v4.z, v4.w};
#pragma unroll
      for (int r = 0; r < 4; ++r)
#pragma unroll
        for (int c = 0; c < 4; ++c) acc[r][c] += pv[r] * vv[c];
    }
#pragma unroll
    for (int r = 0; r < 4; ++r) {
      const int l = i0 + r;
      if (l < 77) {
        const int rr = l / 11, cc = l - rr * 11;
        const int y = ih * 7 + rr, xc = iw * 11 + cc;
        const size_t nat = (size_t)b * 9856 + (size_t)y * 176 + xc;
        uint2 o;
        o.x = pack2(acc[r][0], acc[r][1]);
        o.y = pack2(acc[r][2], acc[r][3]);
        *(uint2*)(onat + nat * DIM + hoff + d0) = o;
      }
    }
  }
}

// ---------- launcher ----------
extern "C" void kernel_launch(void* const* d_in, const int* in_sizes, int n_in,
                              void* d_out, int out_size, void* d_ws, size_t ws_size,
                              hipStream_t stream)
{
  (void)in_sizes; (void)n_in; (void)out_size; (void)ws_size;
  const float* x    = (const float*)d_in[0];
  const float* g1   = (const float*)d_in[1];
  const float* b1   = (const float*)d_in[2];
  const float* wqkv = (const float*)d_in[3];
  const float* bqkv = (const float*)d_in[4];
  const float* wout = (const float*)d_in[5];
  const float* bout = (const float*)d_in[6];
  const float* g2   = (const float*)d_in[7];
  const float* b2   = (const float*)d_in[8];
  const float* w1   = (const float*)d_in[9];
  const float* bf1  = (const float*)d_in[10];
  const float* w2   = (const float*)d_in[11];
  const float* bf2  = (const float*)d_in[12];

  char* ws = (char*)d_ws;
  // workspace layout (bytes):                          size
  u16*   qkv  = (u16*)(ws);                 // M*768*2 = 121110528  (reused: h bf16 M*512*2)
  u16*   xn   = (u16*)(ws + 121110528);     // M*256*2 =  40370176  (reused: xn2)
  u16*   onat = (u16*)(ws + 161480704);     // M*256*2 =  40370176
  float* x2   = (float*)(ws + 201850880);   // M*256*4 =  80740352
  float* outp = (float*)d_out;              // total ws: 282591232 B

  // 1) LN1 + window partition -> xn (bf16, window-row order)
  ln_k<true><<<19712, 256, 0, stream>>>(x, g1, b1, xn);
  // 2) qkv = xn @ Wqkv^T + b   (M x 768)
  gemm_nt<0, 1><<<dim3(616, 6), 256, 0, stream>>>(xn, wqkv, bqkv, nullptr, qkv, 768, 256);
  // 3) per-(window, head) attention -> onat (natural order, bf16)
  attn_win<<<dim3(1024, 8), 256, 0, stream>>>(qkv, onat);
  // 4) x2 = x + onat @ Wout^T + bout   (f32)
  gemm_nt<1, 0><<<dim3(616, 2), 256, 0, stream>>>(onat, wout, bout, x, x2, 256, 256);
  // 5) LN2 -> xn (bf16, natural order)
  ln_k<false><<<19712, 256, 0, stream>>>(x2, g2, b2, xn);
  // 6) h = gelu(xn @ W1^T + b1)  (M x 512, bf16, stored in qkv region)
  gemm_nt<2, 1><<<dim3(616, 4), 256, 0, stream>>>(xn, w1, bf1, nullptr, qkv, 512, 256);
  // 7) out = x2 + h @ W2^T + b2  (f32)
  gemm_nt<1, 0><<<dim3(616, 2), 256, 0, stream>>>(qkv, w2, bf2, x2, outp, 256, 512);
}

// Round 2
// 820.772 us; speedup vs baseline: 1.7810x; 1.7810x over previous
//
#include <hip/hip_runtime.h>
#include <hip/hip_bf16.h>

typedef unsigned short u16;
typedef unsigned int   u32;

typedef __bf16 bf16x8 __attribute__((ext_vector_type(8)));
typedef float  f32x4  __attribute__((ext_vector_type(4)));

// ---------- helpers ----------
__device__ __forceinline__ u16 f2bf(float f) {  // RNE
  u32 u = __float_as_uint(f);
  u += 0x7fffu + ((u >> 16) & 1u);
  return (u16)(u >> 16);
}
__device__ __forceinline__ u32 pack2(float a, float b) {
  return (u32)f2bf(a) | ((u32)f2bf(b) << 16);
}
__device__ __forceinline__ void gld16(const void* g, void* l) {
  __builtin_amdgcn_global_load_lds(
      (const __attribute__((address_space(1))) unsigned int*)g,
      (__attribute__((address_space(3))) unsigned int*)l, 16, 0, 0);
}

// Problem constants
#define TOK_M   78848   // B*N = 8*9856
#define DIM     256
#define NWIN    1024    // 8 * 8 * 16
#define WINL    77      // 7*11

// ---------- weight f32 -> bf16 conversion (all 4 matrices, one launch) ----------
__global__ __launch_bounds__(256)
void cvt_w(const float* __restrict__ w0, const float* __restrict__ w1,
           const float* __restrict__ w2, const float* __restrict__ w3,
           u16* __restrict__ out)
{
  const int i = (blockIdx.x * 256 + threadIdx.x) * 4;  // [0, 524288)
  const float* src; int off;
  if      (i < 196608) { src = w0; off = i; }
  else if (i < 262144) { src = w1; off = i - 196608; }
  else if (i < 393216) { src = w2; off = i - 262144; }
  else                 { src = w3; off = i - 393216; }
  float4 v = *(const float4*)(src + off);
  uint2 o; o.x = pack2(v.x, v.y); o.y = pack2(v.z, v.w);
  *(uint2*)(out + i) = o;
}

// ---------- LayerNorm (+ optional window-partition permutation), fp32 in, bf16 out ----------
template<bool PERM>
__global__ __launch_bounds__(256)
void ln_k(const float* __restrict__ X, const float* __restrict__ g,
          const float* __restrict__ bta, u16* __restrict__ Y)
{
  const int tid  = threadIdx.x;
  const int tok  = blockIdx.x * 4 + (tid >> 6);
  const int lane = tid & 63;
  float4 v = *(const float4*)(X + (size_t)tok * DIM + lane * 4);
  float s = v.x + v.y + v.z + v.w;
#pragma unroll
  for (int off = 32; off; off >>= 1) s += __shfl_xor(s, off);
  const float mu = s * (1.f / 256.f);
  const float dx = v.x - mu, dy = v.y - mu, dz = v.z - mu, dw = v.w - mu;
  float q = dx * dx + dy * dy + dz * dz + dw * dw;
#pragma unroll
  for (int off = 32; off; off >>= 1) q += __shfl_xor(q, off);
  const float rstd = rsqrtf(q * (1.f / 256.f) + 1e-5f);
  float4 gg = *(const float4*)(g + lane * 4);
  float4 bb = *(const float4*)(bta + lane * 4);
  const float y0 = dx * rstd * gg.x + bb.x;
  const float y1 = dy * rstd * gg.y + bb.y;
  const float y2 = dz * rstd * gg.z + bb.z;
  const float y3 = dw * rstd * gg.w + bb.w;
  size_t dest = (size_t)tok;
  if (PERM) {
    const int b  = tok / 9856, n = tok - b * 9856;
    const int y  = n / 176,  xc = n - y * 176;
    const int ih = y / 7,    rr = y - ih * 7;
    const int iw = xc / 11,  cc = xc - iw * 11;
    dest = (size_t)(((b * 8 + ih) * 16 + iw)) * 77 + rr * 11 + cc;
  }
  uint2 o;
  o.x = pack2(y0, y1);
  o.y = pack2(y2, y3);
  *(uint2*)(Y + dest * DIM + lane * 4) = o;
}

// ---------- MFMA GEMM: C[M,N] = A(bf16)[M,K] @ W(bf16)[N,K]^T + bias (+epi) ----------
// 128x128 block tile, 256 threads (4 waves, 2x2), each wave 64x64 = 4x4 MFMA tiles.
// BK=32, 16x16x32 bf16 MFMA. global_load_lds width-16 staging with XOR-swizzled
// 16B blocks so fragment ds_read_b128 is <=2-way bank aliased (free).
// EPI: 0 none, 1 +res(f32), 2 exact GELU. OBF: 1 bf16 out, 0 f32 out.
template<int EPI, int OBF>
__global__ __launch_bounds__(256, 3)
void gemm_mfma(const u16* __restrict__ A, const u16* __restrict__ W,
               const float* __restrict__ bias, const float* res,
               void* Cout, int N, int K)
{
  __shared__ u16 As[4096];  // 128 rows x 32 elems (4x 16B blocks/row, swizzled)
  __shared__ u16 Bs[4096];

  const int tid  = threadIdx.x;
  const int wave = tid >> 6, lane = tid & 63;
  const int wy = wave >> 1, wx = wave & 1;
  const int quad = lane >> 4, l16 = lane & 15;
  const int m0 = blockIdx.x * 128;
  const int n0 = blockIdx.y * 128;

  // staging indices (loop-invariant)
  const int s0 = tid, s1 = tid + 256;
  const int r0 = s0 >> 2, r1 = s1 >> 2;
  const int kb0 = (s0 & 3) ^ (r0 & 3);
  const int kb1 = (s1 & 3) ^ (r1 & 3);
  const u16* Ag0 = A + (size_t)(m0 + r0) * K + kb0 * 8;
  const u16* Ag1 = A + (size_t)(m0 + r1) * K + kb1 * 8;
  const u16* Bg0 = W + (size_t)(n0 + r0) * K + kb0 * 8;
  const u16* Bg1 = W + (size_t)(n0 + r1) * K + kb1 * 8;

  // fragment read bases
  const int kbs = quad ^ (l16 & 3);
  const u16* Ar = &As[(wy * 64 + l16) * 32 + kbs * 8];
  const u16* Br = &Bs[(wx * 64 + l16) * 32 + kbs * 8];

  f32x4 acc[4][4];
#pragma unroll
  for (int i = 0; i < 4; ++i)
#pragma unroll
    for (int j = 0; j < 4; ++j) {
      f32x4 z = {0.f, 0.f, 0.f, 0.f};
      acc[i][j] = z;
    }

  for (int kt = 0; kt < K; kt += 32) {
    gld16(Ag0 + kt, &As[s0 * 8]);
    gld16(Ag1 + kt, &As[s1 * 8]);
    gld16(Bg0 + kt, &Bs[s0 * 8]);
    gld16(Bg1 + kt, &Bs[s1 * 8]);
    __syncthreads();   // drains vmcnt -> staged tile visible
    bf16x8 af[4], bv[4];
#pragma unroll
    for (int i = 0; i < 4; ++i) {
      af[i] = *(const bf16x8*)(Ar + i * 16 * 32);
      bv[i] = *(const bf16x8*)(Br + i * 16 * 32);
    }
#pragma unroll
    for (int mi = 0; mi < 4; ++mi)
#pragma unroll
      for (int ni = 0; ni < 4; ++ni)
        acc[mi][ni] = __builtin_amdgcn_mfma_f32_16x16x32_bf16(
            af[mi], bv[ni], acc[mi][ni], 0, 0, 0);
    __syncthreads();   // all reads done before next stage overwrites
  }

  // epilogue: C/D layout col = lane&15, row = quad*4 + reg
  const int gr0 = m0 + wy * 64 + quad * 4;
  const int gc0 = n0 + wx * 64 + l16;
#pragma unroll
  for (int ni = 0; ni < 4; ++ni) {
    const int gc = gc0 + ni * 16;
    const float bvs = bias[gc];
#pragma unroll
    for (int mi = 0; mi < 4; ++mi) {
      const int gr = gr0 + mi * 16;
      f32x4 a = acc[mi][ni];
#pragma unroll
      for (int e = 0; e < 4; ++e) {
        float v = a[e] + bvs;
        const size_t idx = (size_t)(gr + e) * N + gc;
        if (EPI == 1) v += res[idx];
        else if (EPI == 2) v = 0.5f * v * (1.f + erff(v * 0.70710678118654752f));
        if (OBF) ((u16*)Cout)[idx] = f2bf(v);
        else     ((float*)Cout)[idx] = v;
      }
    }
  }
}

// ---------- Windowed attention, one block per (window, head) ----------
__global__ __launch_bounds__(256)
void attn_win(const u16* __restrict__ qkv, u16* __restrict__ onat)
{
  __shared__ float vs[80][32];
  __shared__ float ss[80][80];
  __shared__ float regC[6720];

  const int tid  = threadIdx.x;
  const int nw   = blockIdx.x;
  const int head = blockIdx.y;
  const size_t base = (size_t)nw * 77 * 768;
  const int hoff = head * 32;

  float* qs = regC;              // qs[d*84 + l]
  float* ks = regC + 32 * 84;    // ks[d*84 + l]

  for (int idx = tid; idx < 80 * 16; idx += 256) {
    const int l = idx >> 4;
    const int d = (idx & 15) << 1;
    float q0 = 0.f, q1 = 0.f, k0 = 0.f, k1 = 0.f, v0 = 0.f, v1 = 0.f;
    if (l < 77) {
      const u32* p = (const u32*)(qkv + base + (size_t)l * 768 + hoff + d);
      const u32 qu = p[0], ku = p[128], vu = p[256];
      q0 = __uint_as_float((qu & 0xffffu) << 16); q1 = __uint_as_float(qu & 0xffff0000u);
      k0 = __uint_as_float((ku & 0xffffu) << 16); k1 = __uint_as_float(ku & 0xffff0000u);
      v0 = __uint_as_float((vu & 0xffffu) << 16); v1 = __uint_as_float(vu & 0xffff0000u);
    }
    qs[(d    ) * 84 + l] = q0;
    qs[(d + 1) * 84 + l] = q1;
    ks[(d    ) * 84 + l] = k0;
    ks[(d + 1) * 84 + l] = k1;
    vs[l][d    ] = v0;
    vs[l][d + 1] = v1;
  }
  __syncthreads();

  const float scale = 0.17677669529663687f;  // 1/sqrt(32)
  for (int t = tid; t < 400; t += 256) {
    const int ti = t / 20, tj = t - ti * 20;
    const int i0 = ti * 4, j0 = tj * 4;
    float acc[4][4] = {{0.f}};
#pragma unroll
    for (int d = 0; d < 32; d += 4) {
#pragma unroll
      for (int dd = 0; dd < 4; ++dd) {
        float4 q4 = *(const float4*)&qs[(d + dd) * 84 + i0];
        float4 k4 = *(const float4*)&ks[(d + dd) * 84 + j0];
        const float qv[4] = {q4.x, q4.y, q4.z, q4.w};
        const float kv[4] = {k4.x, k4.y, k4.z, k4.w};
#pragma unroll
        for (int r = 0; r < 4; ++r)
#pragma unroll
          for (int c = 0; c < 4; ++c) acc[r][c] += qv[r] * kv[c];
      }
    }
#pragma unroll
    for (int r = 0; r < 4; ++r)
      *(float4*)&ss[i0 + r][j0] =
          make_float4(acc[r][0] * scale, acc[r][1] * scale,
                      acc[r][2] * scale, acc[r][3] * scale);
  }
  __syncthreads();

  float* sst = regC;  // p^T: sst[j*84 + i]
  {
    const int wv = tid >> 6, lane = tid & 63;
    for (int i = wv; i < 77; i += 4) {
      const float v0 = ss[i][lane];
      const float v1 = (lane + 64 < 77) ? ss[i][lane + 64] : -1e30f;
      float mx = fmaxf(v0, v1);
#pragma unroll
      for (int off = 32; off; off >>= 1) mx = fmaxf(mx, __shfl_xor(mx, off));
      const float e0 = __expf(v0 - mx);
      const float e1 = __expf(v1 - mx);
      float s = e0 + e1;
#pragma unroll
      for (int off = 32; off; off >>= 1) s += __shfl_xor(s, off);
      const float inv = 1.f / s;
      sst[lane * 84 + i] = e0 * inv;
      if (lane + 64 < 80) sst[(lane + 64) * 84 + i] = e1 * inv;
    }
  }
  __syncthreads();

  const int b  = nw >> 7;
  const int ih = (nw >> 4) & 7;
  const int iw = nw & 15;
  for (int t = tid; t < 160; t += 256) {
    const int ti = t >> 3, tc = t & 7;
    const int i0 = ti * 4, d0 = tc * 4;
    float acc[4][4] = {{0.f}};
    for (int j = 0; j < 80; ++j) {
      float4 p4 = *(const float4*)&sst[j * 84 + i0];
      float4 v4 = *(const float4*)&vs[j][d0];
      const float pv[4] = {p4.x, p4.y, p4.z, p4.w};
      const float vv[4] = {v4.x, v4.y, v4.z, v4.w};
#pragma unroll
      for (int r = 0; r < 4; ++r)
#pragma unroll
        for (int c = 0; c < 4; ++c) acc[r][c] += pv[r] * vv[c];
    }
#pragma unroll
    for (int r = 0; r < 4; ++r) {
      const int l = i0 + r;
      if (l < 77) {
        const int rr = l / 11, cc = l - rr * 11;
        const int y = ih * 7 + rr, xc = iw * 11 + cc;
        const size_t nat = (size_t)b * 9856 + (size_t)y * 176 + xc;
        uint2 o;
        o.x = pack2(acc[r][0], acc[r][1]);
        o.y = pack2(acc[r][2], acc[r][3]);
        *(uint2*)(onat + nat * DIM + hoff + d0) = o;
      }
    }
  }
}

// ---------- launcher ----------
extern "C" void kernel_launch(void* const* d_in, const int* in_sizes, int n_in,
                              void* d_out, int out_size, void* d_ws, size_t ws_size,
                              hipStream_t stream)
{
  (void)in_sizes; (void)n_in; (void)out_size; (void)ws_size;
  const float* x    = (const float*)d_in[0];
  const float* g1   = (const float*)d_in[1];
  const float* b1   = (const float*)d_in[2];
  const float* wqkv = (const float*)d_in[3];
  const float* bqkv = (const float*)d_in[4];
  const float* wout = (const float*)d_in[5];
  const float* bout = (const float*)d_in[6];
  const float* g2   = (const float*)d_in[7];
  const float* b2   = (const float*)d_in[8];
  const float* w1   = (const float*)d_in[9];
  const float* bf1  = (const float*)d_in[10];
  const float* w2   = (const float*)d_in[11];
  const float* bf2  = (const float*)d_in[12];

  char* ws = (char*)d_ws;
  // workspace layout (bytes):
  u16*   qkv  = (u16*)(ws);                 // M*768*2 = 121110528  (reused: h = M*512*2)
  u16*   xn   = (u16*)(ws + 121110528);     // M*256*2 =  40370176  (reused: xn2)
  u16*   onat = (u16*)(ws + 161480704);     // M*256*2 =  40370176
  u16*   wb   = (u16*)(ws + 201850880);     // 524288*2 = 1048576   -> total 202899456 B
  u16*   wqkv_b = wb;
  u16*   wout_b = wb + 196608;
  u16*   w1_b   = wb + 262144;
  u16*   w2_b   = wb + 393216;
  float* x2   = (float*)d_out;              // x2 lives in d_out (step 7 in-place residual)

  // 0) weights f32 -> bf16
  cvt_w<<<512, 256, 0, stream>>>(wqkv, wout, w1, w2, wb);
  // 1) LN1 + window partition -> xn (bf16, window-row order)
  ln_k<true><<<19712, 256, 0, stream>>>(x, g1, b1, xn);
  // 2) qkv = xn @ Wqkv^T + b   (M x 768, bf16)
  gemm_mfma<0, 1><<<dim3(616, 6), 256, 0, stream>>>(xn, wqkv_b, bqkv, nullptr, qkv, 768, 256);
  // 3) per-(window, head) attention -> onat (natural order, bf16)
  attn_win<<<dim3(1024, 8), 256, 0, stream>>>(qkv, onat);
  // 4) x2 = x + onat @ Wout^T + bout   (f32, into d_out)
  gemm_mfma<1, 0><<<dim3(616, 2), 256, 0, stream>>>(onat, wout_b, bout, x, x2, 256, 256);
  // 5) LN2 -> xn (bf16, natural order)
  ln_k<false><<<19712, 256, 0, stream>>>(x2, g2, b2, xn);
  // 6) h = gelu(xn @ W1^T + b1)  (M x 512, bf16, in qkv region)
  gemm_mfma<2, 1><<<dim3(616, 4), 256, 0, stream>>>(xn, w1_b, bf1, nullptr, qkv, 512, 256);
  // 7) out = x2 + h @ W2^T + b2  (f32, in-place on d_out)
  gemm_mfma<1, 0><<<dim3(616, 2), 256, 0, stream>>>(qkv, w2_b, bf2, x2, x2, 256, 512);
}

// Round 3
// 603.105 us; speedup vs baseline: 2.4238x; 1.3609x over previous
//
#include <hip/hip_runtime.h>
#include <hip/hip_bf16.h>

typedef unsigned short u16;
typedef unsigned int   u32;

typedef __bf16 bf16x8 __attribute__((ext_vector_type(8)));
typedef float  f32x4  __attribute__((ext_vector_type(4)));

// ---------- helpers ----------
__device__ __forceinline__ u16 f2bf(float f) {  // RNE
  u32 u = __float_as_uint(f);
  u += 0x7fffu + ((u >> 16) & 1u);
  return (u16)(u >> 16);
}
__device__ __forceinline__ u32 pack2(float a, float b) {
  return (u32)f2bf(a) | ((u32)f2bf(b) << 16);
}
__device__ __forceinline__ void gld16(const void* g, void* l) {
  __builtin_amdgcn_global_load_lds(
      (const __attribute__((address_space(1))) unsigned int*)g,
      (__attribute__((address_space(3))) unsigned int*)l, 16, 0, 0);
}

// Problem constants
#define TOK_M   78848   // B*N = 8*9856
#define DIM     256
#define NWIN    1024    // 8 * 8 * 16
#define WINL    77      // 7*11

// ---------- weight f32 -> bf16 conversion (all 4 matrices, one launch) ----------
__global__ __launch_bounds__(256)
void cvt_w(const float* __restrict__ w0, const float* __restrict__ w1,
           const float* __restrict__ w2, const float* __restrict__ w3,
           u16* __restrict__ out)
{
  const int i = (blockIdx.x * 256 + threadIdx.x) * 4;  // [0, 524288)
  const float* src; int off;
  if      (i < 196608) { src = w0; off = i; }
  else if (i < 262144) { src = w1; off = i - 196608; }
  else if (i < 393216) { src = w2; off = i - 262144; }
  else                 { src = w3; off = i - 393216; }
  float4 v = *(const float4*)(src + off);
  uint2 o; o.x = pack2(v.x, v.y); o.y = pack2(v.z, v.w);
  *(uint2*)(out + i) = o;
}

// ---------- LayerNorm (+ optional window-partition permutation), fp32 in, bf16 out ----------
template<bool PERM>
__global__ __launch_bounds__(256)
void ln_k(const float* __restrict__ X, const float* __restrict__ g,
          const float* __restrict__ bta, u16* __restrict__ Y)
{
  const int tid  = threadIdx.x;
  const int tok  = blockIdx.x * 4 + (tid >> 6);
  const int lane = tid & 63;
  float4 v = *(const float4*)(X + (size_t)tok * DIM + lane * 4);
  float s = v.x + v.y + v.z + v.w;
#pragma unroll
  for (int off = 32; off; off >>= 1) s += __shfl_xor(s, off);
  const float mu = s * (1.f / 256.f);
  const float dx = v.x - mu, dy = v.y - mu, dz = v.z - mu, dw = v.w - mu;
  float q = dx * dx + dy * dy + dz * dz + dw * dw;
#pragma unroll
  for (int off = 32; off; off >>= 1) q += __shfl_xor(q, off);
  const float rstd = rsqrtf(q * (1.f / 256.f) + 1e-5f);
  float4 gg = *(const float4*)(g + lane * 4);
  float4 bb = *(const float4*)(bta + lane * 4);
  const float y0 = dx * rstd * gg.x + bb.x;
  const float y1 = dy * rstd * gg.y + bb.y;
  const float y2 = dz * rstd * gg.z + bb.z;
  const float y3 = dw * rstd * gg.w + bb.w;
  size_t dest = (size_t)tok;
  if (PERM) {
    const int b  = tok / 9856, n = tok - b * 9856;
    const int y  = n / 176,  xc = n - y * 176;
    const int ih = y / 7,    rr = y - ih * 7;
    const int iw = xc / 11,  cc = xc - iw * 11;
    dest = (size_t)(((b * 8 + ih) * 16 + iw)) * 77 + rr * 11 + cc;
  }
  uint2 o;
  o.x = pack2(y0, y1);
  o.y = pack2(y2, y3);
  *(uint2*)(Y + dest * DIM + lane * 4) = o;
}

// ---------- MFMA GEMM: C[M,N] = A(bf16)[M,K] @ W(bf16)[N,K]^T + bias (+epi) ----------
template<int EPI, int OBF>
__global__ __launch_bounds__(256, 3)
void gemm_mfma(const u16* __restrict__ A, const u16* __restrict__ W,
               const float* __restrict__ bias, const float* res,
               void* Cout, int N, int K)
{
  __shared__ u16 As[4096];  // 128 rows x 32 elems (4x 16B blocks/row, swizzled)
  __shared__ u16 Bs[4096];

  const int tid  = threadIdx.x;
  const int wave = tid >> 6, lane = tid & 63;
  const int wy = wave >> 1, wx = wave & 1;
  const int quad = lane >> 4, l16 = lane & 15;
  const int m0 = blockIdx.x * 128;
  const int n0 = blockIdx.y * 128;

  const int s0 = tid, s1 = tid + 256;
  const int r0 = s0 >> 2, r1 = s1 >> 2;
  const int kb0 = (s0 & 3) ^ (r0 & 3);
  const int kb1 = (s1 & 3) ^ (r1 & 3);
  const u16* Ag0 = A + (size_t)(m0 + r0) * K + kb0 * 8;
  const u16* Ag1 = A + (size_t)(m0 + r1) * K + kb1 * 8;
  const u16* Bg0 = W + (size_t)(n0 + r0) * K + kb0 * 8;
  const u16* Bg1 = W + (size_t)(n0 + r1) * K + kb1 * 8;

  const int kbs = quad ^ (l16 & 3);
  const u16* Ar = &As[(wy * 64 + l16) * 32 + kbs * 8];
  const u16* Br = &Bs[(wx * 64 + l16) * 32 + kbs * 8];

  f32x4 acc[4][4];
#pragma unroll
  for (int i = 0; i < 4; ++i)
#pragma unroll
    for (int j = 0; j < 4; ++j) {
      f32x4 z = {0.f, 0.f, 0.f, 0.f};
      acc[i][j] = z;
    }

  for (int kt = 0; kt < K; kt += 32) {
    gld16(Ag0 + kt, &As[s0 * 8]);
    gld16(Ag1 + kt, &As[s1 * 8]);
    gld16(Bg0 + kt, &Bs[s0 * 8]);
    gld16(Bg1 + kt, &Bs[s1 * 8]);
    __syncthreads();
    bf16x8 af[4], bv[4];
#pragma unroll
    for (int i = 0; i < 4; ++i) {
      af[i] = *(const bf16x8*)(Ar + i * 16 * 32);
      bv[i] = *(const bf16x8*)(Br + i * 16 * 32);
    }
#pragma unroll
    for (int mi = 0; mi < 4; ++mi)
#pragma unroll
      for (int ni = 0; ni < 4; ++ni)
        acc[mi][ni] = __builtin_amdgcn_mfma_f32_16x16x32_bf16(
            af[mi], bv[ni], acc[mi][ni], 0, 0, 0);
    __syncthreads();
  }

  const int gr0 = m0 + wy * 64 + quad * 4;
  const int gc0 = n0 + wx * 64 + l16;
#pragma unroll
  for (int ni = 0; ni < 4; ++ni) {
    const int gc = gc0 + ni * 16;
    const float bvs = bias[gc];
#pragma unroll
    for (int mi = 0; mi < 4; ++mi) {
      const int gr = gr0 + mi * 16;
      f32x4 a = acc[mi][ni];
#pragma unroll
      for (int e = 0; e < 4; ++e) {
        float v = a[e] + bvs;
        const size_t idx = (size_t)(gr + e) * N + gc;
        if (EPI == 1) v += res[idx];
        else if (EPI == 2) v = 0.5f * v * (1.f + erff(v * 0.70710678118654752f));
        if (OBF) ((u16*)Cout)[idx] = f2bf(v);
        else     ((float*)Cout)[idx] = v;
      }
    }
  }
}

// ---------- MFMA windowed attention: one WAVE per (window, head) ----------
// 2 waves/block (private LDS P-buffers, no barriers). Q,K,V fragments loaded
// directly from global in MFMA layouts. S = Q@K^T (25 mfma), register softmax
// (shfl_xor over l16 group), P -> LDS (bf16, stride 104: 16B-aligned rows,
// bank period 8 => <=2-way), O = P@V (30 mfma), store window-reversed.
#define PSTR 104
__global__ __launch_bounds__(128)
void attn_mfma(const u16* __restrict__ qkv, u16* __restrict__ onat)
{
  __shared__ __bf16 Pb[2][80 * PSTR];

  const int tid  = threadIdx.x;
  const int wave = tid >> 6, lane = tid & 63;
  const int quad = lane >> 4, l16 = lane & 15;
  const int pair = blockIdx.x * 2 + wave;     // [0, 8192)
  const int nw   = pair >> 3, head = pair & 7;
  const size_t base = (size_t)nw * 77 * 768;
  const int hoff = head * 32;
  __bf16* P = Pb[wave];

  // ---- zero P cols 80..95 (NaN-safety for padded K-steps) ----
  {
    uint4 z = {0, 0, 0, 0};
    for (int r = lane; r < 80; r += 64) {
      *(uint4*)(P + r * PSTR + 80) = z;
      *(uint4*)(P + r * PSTR + 88) = z;
    }
  }

  // ---- Q, K fragments straight from global (lane l16 = token row) ----
  bf16x8 qf[5], kf[5];
  const u16* qp = qkv + base + hoff + quad * 8;
#pragma unroll
  for (int mi = 0; mi < 5; ++mi) {
    const size_t row = (size_t)(l16 + 16 * mi) * 768;
    qf[mi] = *(const bf16x8*)(qp + row);          // q block
    kf[mi] = *(const bf16x8*)(qp + row + 256);    // k block
  }

  // ---- scores S[80][80] in 25 C-tiles ----
  f32x4 s[5][5];
#pragma unroll
  for (int mi = 0; mi < 5; ++mi)
#pragma unroll
    for (int ni = 0; ni < 5; ++ni) {
      f32x4 z = {0.f, 0.f, 0.f, 0.f};
      s[mi][ni] = z;
    }
#pragma unroll
  for (int mi = 0; mi < 5; ++mi)
#pragma unroll
    for (int ni = 0; ni < 5; ++ni)
      s[mi][ni] = __builtin_amdgcn_mfma_f32_16x16x32_bf16(
          qf[mi], kf[ni], s[mi][ni], 0, 0, 0);

  // ---- V fragments (b-layout: lane l16 = d, k = quad*8+jj); k>=77 -> 0 ----
  bf16x8 vf[3][2];
  {
    const __bf16* vbb = (const __bf16*)(qkv + base + 512 + hoff + l16);
#pragma unroll
    for (int ks = 0; ks < 3; ++ks)
#pragma unroll
      for (int ni = 0; ni < 2; ++ni)
#pragma unroll
        for (int jj = 0; jj < 8; ++jj) {
          const int k = ks * 32 + quad * 8 + jj;
          vf[ks][ni][jj] = (k < 77) ? vbb[(size_t)k * 768 + 16 * ni] : (__bf16)0.f;
        }
  }

  // ---- mask cols j >= 77 (j = l16 + 16*ni; only ni==4, l16>=13) ----
  if (l16 >= 13) {
#pragma unroll
    for (int mi = 0; mi < 5; ++mi)
#pragma unroll
      for (int e = 0; e < 4; ++e) s[mi][4][e] = -1e30f;
  }

  // ---- register softmax per row (row = quad*4+e+16*mi) ----
  const float c = 0.17677669529663687f * 1.4426950408889634f;  // scale*log2(e)
  float inv[5][4];
#pragma unroll
  for (int mi = 0; mi < 5; ++mi)
#pragma unroll
    for (int e = 0; e < 4; ++e) {
      float mx = s[mi][0][e];
#pragma unroll
      for (int ni = 1; ni < 5; ++ni) mx = fmaxf(mx, s[mi][ni][e]);
#pragma unroll
      for (int off = 1; off < 16; off <<= 1) mx = fmaxf(mx, __shfl_xor(mx, off));
      float sum = 0.f;
#pragma unroll
      for (int ni = 0; ni < 5; ++ni) {
        const float ev = exp2f((s[mi][ni][e] - mx) * c);
        s[mi][ni][e] = ev;
        sum += ev;
      }
#pragma unroll
      for (int off = 1; off < 16; off <<= 1) sum += __shfl_xor(sum, off);
      inv[mi][e] = 1.f / sum;
    }

  // ---- P -> LDS (bf16), A-operand layout [m][k] ----
#pragma unroll
  for (int mi = 0; mi < 5; ++mi)
#pragma unroll
    for (int e = 0; e < 4; ++e) {
      const int m = quad * 4 + e + 16 * mi;
#pragma unroll
      for (int ni = 0; ni < 5; ++ni)
        P[m * PSTR + l16 + 16 * ni] = (__bf16)(s[mi][ni][e] * inv[mi][e]);
    }

  // ---- O = P @ V ----
  f32x4 o[5][2];
#pragma unroll
  for (int mi = 0; mi < 5; ++mi)
#pragma unroll
    for (int ni = 0; ni < 2; ++ni) {
      f32x4 z = {0.f, 0.f, 0.f, 0.f};
      o[mi][ni] = z;
    }
#pragma unroll
  for (int ks = 0; ks < 3; ++ks)
#pragma unroll
    for (int mi = 0; mi < 5; ++mi) {
      const bf16x8 af = *(const bf16x8*)(P + (l16 + 16 * mi) * PSTR + ks * 32 + quad * 8);
#pragma unroll
      for (int ni = 0; ni < 2; ++ni)
        o[mi][ni] = __builtin_amdgcn_mfma_f32_16x16x32_bf16(
            af, vf[ks][ni], o[mi][ni], 0, 0, 0);
    }

  // ---- store O, window-reversed, bf16 ----
  const int b  = nw >> 7;
  const int ih = (nw >> 4) & 7;
  const int iw = nw & 15;
#pragma unroll
  for (int mi = 0; mi < 5; ++mi)
#pragma unroll
    for (int e = 0; e < 4; ++e) {
      const int t = quad * 4 + e + 16 * mi;
      if (t < 77) {
        const int rr = t / 11, cc = t - rr * 11;
        const int y = ih * 7 + rr, xc = iw * 11 + cc;
        const size_t nat = (size_t)b * 9856 + (size_t)y * 176 + xc;
        u16* dst = onat + nat * DIM + hoff + l16;
        dst[0]  = f2bf(o[mi][0][e]);
        dst[16] = f2bf(o[mi][1][e]);
      }
    }
}

// ---------- launcher ----------
extern "C" void kernel_launch(void* const* d_in, const int* in_sizes, int n_in,
                              void* d_out, int out_size, void* d_ws, size_t ws_size,
                              hipStream_t stream)
{
  (void)in_sizes; (void)n_in; (void)out_size; (void)ws_size;
  const float* x    = (const float*)d_in[0];
  const float* g1   = (const float*)d_in[1];
  const float* b1   = (const float*)d_in[2];
  const float* wqkv = (const float*)d_in[3];
  const float* bqkv = (const float*)d_in[4];
  const float* wout = (const float*)d_in[5];
  const float* bout = (const float*)d_in[6];
  const float* g2   = (const float*)d_in[7];
  const float* b2   = (const float*)d_in[8];
  const float* w1   = (const float*)d_in[9];
  const float* bf1  = (const float*)d_in[10];
  const float* w2   = (const float*)d_in[11];
  const float* bf2  = (const float*)d_in[12];

  char* ws = (char*)d_ws;
  u16*   qkv  = (u16*)(ws);                 // M*768*2 = 121110528  (reused: h = M*512*2)
  u16*   xn   = (u16*)(ws + 121110528);     // M*256*2 =  40370176  (reused: xn2)
  u16*   onat = (u16*)(ws + 161480704);     // M*256*2 =  40370176
  u16*   wb   = (u16*)(ws + 201850880);     // 524288*2 = 1048576
  u16*   wqkv_b = wb;
  u16*   wout_b = wb + 196608;
  u16*   w1_b   = wb + 262144;
  u16*   w2_b   = wb + 393216;
  float* x2   = (float*)d_out;              // x2 lives in d_out

  cvt_w<<<512, 256, 0, stream>>>(wqkv, wout, w1, w2, wb);
  ln_k<true><<<19712, 256, 0, stream>>>(x, g1, b1, xn);
  gemm_mfma<0, 1><<<dim3(616, 6), 256, 0, stream>>>(xn, wqkv_b, bqkv, nullptr, qkv, 768, 256);
  attn_mfma<<<4096, 128, 0, stream>>>(qkv, onat);
  gemm_mfma<1, 0><<<dim3(616, 2), 256, 0, stream>>>(onat, wout_b, bout, x, x2, 256, 256);
  ln_k<false><<<19712, 256, 0, stream>>>(x2, g2, b2, xn);
  gemm_mfma<2, 1><<<dim3(616, 4), 256, 0, stream>>>(xn, w1_b, bf1, nullptr, qkv, 512, 256);
  gemm_mfma<1, 0><<<dim3(616, 2), 256, 0, stream>>>(qkv, w2_b, bf2, x2, x2, 256, 512);
}